// Round 7
// baseline (1287.410 us; speedup 1.0000x reference)
//
#include <hip/hip_runtime.h>
#include <math.h>

#define NCLS 9

typedef __attribute__((ext_vector_type(8))) short short8;
typedef __attribute__((ext_vector_type(4))) float f32x4;

__device__ __forceinline__ unsigned short f2bf(float f) {
    unsigned int u = __float_as_uint(f);
    return (unsigned short)((u + 0x7fffu + ((u >> 16) & 1u)) >> 16);  // RNE
}

__device__ __forceinline__ short8 as_s8(uint4 v) {
    union { uint4 u; short8 s; } x; x.u = v; return x.s;
}

__device__ __forceinline__ float fast_tanh(float x) {
    // tanh(x) = 1 - 2/(2^(x*2*log2e) + 1); saturates correctly at +/-1
    float s = x * 2.885390081777927f;
    float e, r;
    asm("v_exp_f32 %0, %1" : "=v"(e) : "v"(s));
    asm("v_rcp_f32 %0, %1" : "=v"(r) : "v"(e + 1.0f));
    return fmaf(-2.0f, r, 1.0f);
}

// Fused 2-layer persistent MFMA RNN. 32 blocks x 16 batch rows, 256 threads
// (4 waves). Wave w owns 64 output cols as 4 B-tiles (128 pinned VGPR).
// Tile (u,v) (u,v in {0,1}) covers cols w*64 + u*32 + 2c + v (c = lane&15),
// so each lane's per-row outputs pair up: (u,0)+(u,1) -> one v_cvt_pk_bf16_f32
// + one b32 LDS write at column-pair cp = w*32 + u*16 + c.
//
// h LDS layout (R6): 512 cells x 16B; cell (kk,g2,m) holds k=kk*32+g2*8+e of
// row m at index kk*64+g2*16+(m ^ ((4*kk+g2)&15)).
//  - A-read (per kk): contiguous permuted 1KB -> conflict-free ds_read_b128.
//  - h-write: b32, banks 16*((g^u)&1)+4*(r^q)+s -> exactly 2-way (free).
// DS traffic: 4 waves x 8KB = 32KB/step (half of R6).
//
// KEY: bfrag pins are INSIDE the t-loop. The "+v" volatile asm each iteration
// makes bfrag opaque-modified -> loop-carried register dependence -> the
// allocator cannot rematerialize U loads per step (R1/R3/R4 failure mode).
__global__ __launch_bounds__(256, 1) void rnn_fused_kernel(
    const float* __restrict__ x,     // [B, 1024]
    const float* __restrict__ W1, const float* __restrict__ U1, const float* __restrict__ b1,
    const float* __restrict__ W2, const float* __restrict__ U2, const float* __restrict__ b2,
    float* __restrict__ h2out)       // [B, 256]
{
    const int tid  = threadIdx.x;
    const int w    = tid >> 6;    // wave 0..3
    const int lane = tid & 63;
    const int g    = lane >> 4;
    const int l16  = lane & 15;
    const int b0   = blockIdx.x << 4;

    __shared__ uint4 hbuf[2][512];       // 2 x 8KB, cell layout above
    __shared__ float xall[1024][16];     // 64KB: x staged [t][row]
    __shared__ float seq2[256][16];      // 16KB: layer-2 input [col][row]

    // ---- stage all of x (once) + zero h buffer 0 ----
    {
        const float4* x4 = (const float4*)x;
        #pragma unroll
        for (int i = 0; i < 16; ++i) {
            const int idx = tid + i * 256;
            const int row = idx >> 8, tq = idx & 255;
            const float4 v = x4[(b0 + row) * 256 + tq];
            xall[tq * 4 + 0][row] = v.x;
            xall[tq * 4 + 1][row] = v.y;
            xall[tq * 4 + 2][row] = v.z;
            xall[tq * 4 + 3][row] = v.w;
        }
        for (int idx = tid; idx < 2048; idx += 256)
            ((unsigned int*)hbuf[0])[idx] = 0u;
    }

    // ---- hoisted LDS byte offsets ----
    int rd_off[8];
    #pragma unroll
    for (int kk = 0; kk < 8; ++kk)
        rd_off[kk] = ((kk * 64 + g * 16) + (l16 ^ ((kk * 4 + g) & 15))) << 4;
    const int q = l16 >> 2, s4 = l16 & 3;
    int wr_off[4][2];
    #pragma unroll
    for (int r = 0; r < 4; ++r) {
        #pragma unroll
        for (int u = 0; u < 2; ++u) {
            const int K = 2 * w + u;
            const int m = 4 * g + r;
            wr_off[r][u] = ((K * 64 + q * 16 + (m ^ ((4 * K + q) & 15))) << 4) + 4 * s4;
        }
    }
    char* const hbase = (char*)hbuf;

#pragma unroll 1
    for (int p = 0; p < 2; ++p) {
        const float* W    = p ? W2 : W1;
        const float* U    = p ? U2 : U1;
        const float* bias = p ? b2 : b1;
        const int    T    = p ? 256 : 1024;

        // ---- B-fragments (bf16, registers); tile (u,v): col = w*64+u*32+2c+v
        uint4 bfrag[2][2][8];
        #pragma unroll
        for (int u = 0; u < 2; ++u) {
            #pragma unroll
            for (int v = 0; v < 2; ++v) {
                const int col = w * 64 + u * 32 + 2 * l16 + v;
                #pragma unroll
                for (int kk = 0; kk < 8; ++kk) {
                    unsigned int d[4];
                    #pragma unroll
                    for (int pr = 0; pr < 4; ++pr) {
                        const int k0 = kk * 32 + g * 8 + 2 * pr;
                        d[pr] = (unsigned)f2bf(U[k0 * 256 + col])
                              | ((unsigned)f2bf(U[(k0 + 1) * 256 + col]) << 16);
                    }
                    bfrag[u][v][kk] = make_uint4(d[0], d[1], d[2], d[3]);
                }
            }
        }

        // W/bias for col pairs (u): cols w*64 + u*32 + 2*l16 + {0,1}
        const float2 wv[2] = { *(const float2*)&W[w * 64 + 2 * l16],
                               *(const float2*)&W[w * 64 + 32 + 2 * l16] };
        const float2 bv[2] = { *(const float2*)&bias[w * 64 + 2 * l16],
                               *(const float2*)&bias[w * 64 + 32 + 2 * l16] };

        if (p == 1) {
            for (int idx = tid; idx < 2048; idx += 256)
                ((unsigned int*)hbuf[0])[idx] = 0u;
        }
        __syncthreads();

        for (int t = 0; t < T; ++t) {
            // ---- in-loop pins: force bfrag resident across iterations ----
            #pragma unroll
            for (int u = 0; u < 2; ++u)
                #pragma unroll
                for (int v = 0; v < 2; ++v)
                    #pragma unroll
                    for (int kk = 0; kk < 8; ++kk)
                        asm volatile("" : "+v"(bfrag[u][v][kk].x), "+v"(bfrag[u][v][kk].y),
                                          "+v"(bfrag[u][v][kk].z), "+v"(bfrag[u][v][kk].w));

            char* const hcur = hbase + ((t & 1) << 13);
            char* const hnxt = hbase + (((t & 1) ^ 1) << 13);

            // A-fragments: 8 x ds_read_b128, conflict-free
            uint4 a[8];
            #pragma unroll
            for (int kk = 0; kk < 8; ++kk)
                a[kk] = *(const uint4*)(hcur + rd_off[kk]);

            const float4 sv = p ? *(const float4*)&seq2[t][4 * g]
                                : *(const float4*)&xall[t][4 * g];

            // 8 independent 4-deep MFMA chains (4 tiles x even/odd kk)
            f32x4 accE[2][2], accO[2][2];
            #pragma unroll
            for (int u = 0; u < 2; ++u)
                #pragma unroll
                for (int v = 0; v < 2; ++v) {
                    accE[u][v] = (f32x4){0.f, 0.f, 0.f, 0.f};
                    accO[u][v] = (f32x4){0.f, 0.f, 0.f, 0.f};
                }
            #pragma unroll
            for (int kp = 0; kp < 4; ++kp) {
                #pragma unroll
                for (int u = 0; u < 2; ++u)
                    #pragma unroll
                    for (int v = 0; v < 2; ++v) {
                        accE[u][v] = __builtin_amdgcn_mfma_f32_16x16x32_bf16(
                            as_s8(a[2 * kp]), as_s8(bfrag[u][v][2 * kp]), accE[u][v], 0, 0, 0);
                        accO[u][v] = __builtin_amdgcn_mfma_f32_16x16x32_bf16(
                            as_s8(a[2 * kp + 1]), as_s8(bfrag[u][v][2 * kp + 1]), accO[u][v], 0, 0, 0);
                    }
            }

            const float svr[4] = {sv.x, sv.y, sv.z, sv.w};
            #pragma unroll
            for (int r = 0; r < 4; ++r) {
                #pragma unroll
                for (int u = 0; u < 2; ++u) {
                    const float v0 = (accE[u][0][r] + accO[u][0][r])
                                   + fmaf(svr[r], wv[u].x, bv[u].x);
                    const float v1 = (accE[u][1][r] + accO[u][1][r])
                                   + fmaf(svr[r], wv[u].y, bv[u].y);
                    const float h0 = fast_tanh(v0);
                    const float h1 = fast_tanh(v1);
                    unsigned pk;
                    asm("v_cvt_pk_bf16_f32 %0, %1, %2" : "=v"(pk) : "v"(h0), "v"(h1));
                    *(unsigned int*)(hnxt + wr_off[r][u]) = pk;

                    if (t == T - 1) {
                        const int m    = 4 * g + r;
                        const int colb = w * 64 + u * 32 + 2 * l16;
                        if (p == 0) {
                            seq2[colb][m]     = h0;
                            seq2[colb + 1][m] = h1;
                        } else {
                            *(float2*)&h2out[(b0 + m) * 256 + colb] = make_float2(h0, h1);
                        }
                    }
                }
            }
            __syncthreads();
        }
    }
}

// Tiny MLP head: one block per batch row, 128 threads.
__global__ __launch_bounds__(128) void mlp_kernel(
    const float* __restrict__ h2,
    const float* __restrict__ Wd1, const float* __restrict__ bd1,
    const float* __restrict__ Wd2, const float* __restrict__ bd2,
    const float* __restrict__ Wd3, const float* __restrict__ bd3,
    const float* __restrict__ Wd4, const float* __restrict__ bd4,
    float* __restrict__ out)
{
    const int b   = blockIdx.x;
    const int tid = threadIdx.x;

    __shared__ float hin[256];
    __shared__ float z1[128];
    __shared__ float z2[64];
    __shared__ float z3[32];

    hin[tid]       = h2[b * 256 + tid];
    hin[tid + 128] = h2[b * 256 + tid + 128];
    __syncthreads();

    {
        float a = bd1[tid];
#pragma unroll 8
        for (int i = 0; i < 256; ++i) a += hin[i] * Wd1[i * 128 + tid];
        z1[tid] = fmaxf(a, 0.0f);
    }
    __syncthreads();
    if (tid < 64) {
        float a = bd2[tid];
#pragma unroll 8
        for (int i = 0; i < 128; ++i) a += z1[i] * Wd2[i * 64 + tid];
        z2[tid] = fmaxf(a, 0.0f);
    }
    __syncthreads();
    if (tid < 32) {
        float a = bd3[tid];
#pragma unroll 8
        for (int i = 0; i < 64; ++i) a += z2[i] * Wd3[i * 32 + tid];
        z3[tid] = fmaxf(a, 0.0f);
    }
    __syncthreads();
    if (tid < NCLS) {
        float a = bd4[tid];
#pragma unroll
        for (int i = 0; i < 32; ++i) a += z3[i] * Wd4[i * NCLS + tid];
        out[b * NCLS + tid] = a;
    }
}

extern "C" void kernel_launch(void* const* d_in, const int* in_sizes, int n_in,
                              void* d_out, int out_size, void* d_ws, size_t ws_size,
                              hipStream_t stream) {
    const float* x   = (const float*)d_in[0];
    const float* W1  = (const float*)d_in[1];
    const float* U1  = (const float*)d_in[2];
    const float* b1  = (const float*)d_in[3];
    const float* W2  = (const float*)d_in[4];
    const float* U2  = (const float*)d_in[5];
    const float* b2  = (const float*)d_in[6];
    const float* Wd1 = (const float*)d_in[7];
    const float* bd1 = (const float*)d_in[8];
    const float* Wd2 = (const float*)d_in[9];
    const float* bd2 = (const float*)d_in[10];
    const float* Wd3 = (const float*)d_in[11];
    const float* bd3 = (const float*)d_in[12];
    const float* Wd4 = (const float*)d_in[13];
    const float* bd4 = (const float*)d_in[14];

    float* out = (float*)d_out;
    float* h2  = (float*)d_ws;        // 512*256 fp32

    rnn_fused_kernel<<<32, 256, 0, stream>>>(x, W1, U1, b1, W2, U2, b2, h2);
    mlp_kernel<<<512, 128, 0, stream>>>(h2, Wd1, bd1, Wd2, bd2, Wd3, bd3, Wd4, bd4, out);
}

// Round 8
// 785.319 us; speedup vs baseline: 1.6393x; 1.6393x over previous
//
#include <hip/hip_runtime.h>
#include <math.h>

#define NCLS 9

typedef __attribute__((ext_vector_type(8))) short short8;
typedef __attribute__((ext_vector_type(4))) float f32x4;

__device__ __forceinline__ unsigned short f2bf(float f) {
    unsigned int u = __float_as_uint(f);
    return (unsigned short)((u + 0x7fffu + ((u >> 16) & 1u)) >> 16);  // RNE
}

__device__ __forceinline__ short8 as_s8(uint4 v) {
    union { uint4 u; short8 s; } x; x.u = v; return x.s;
}

__device__ __forceinline__ float fast_tanh(float x) {
    // tanh(x) = 1 - 2/(2^(x*2*log2e) + 1); saturates correctly at +/-1
    float s = x * 2.885390081777927f;
    float e, r;
    asm("v_exp_f32 %0, %1" : "=v"(e) : "v"(s));
    asm("v_rcp_f32 %0, %1" : "=v"(r) : "v"(e + 1.0f));
    return fmaf(-2.0f, r, 1.0f);
}

// Fused 2-layer persistent MFMA RNN (R6 structure + chain-shortening).
// 32 blocks x 16 batch rows, 512 threads (8 waves). Wave w owns 32 output
// cols (2 B-tiles, 64 pinned VGPR), paired-column map col = w*32 + 2c + t2.
//
// h LDS layout: 512 cells x 16B; cell (kk,g2,m) holds k=kk*32+g2*8+e of row m
// at index kk*64+g2*16+(m ^ ((4*kk+g2)&15)).
//  - A-read (per kk): contiguous permuted 1KB -> conflict-free ds_read_b128.
//  - h-write: b32, exactly 2-way bank aliasing (free).
//
// Chain-shortening vs R6:
//  - accE is initialized with fmaf(sv, W, b) (input projection + bias) BEFORE
//    the MFMA chain -> that VALU work overlaps the post-barrier ds_read
//    latency instead of sitting in the post-MFMA epilogue.
//  - sv for step t+1 is prefetched from static LDS (xall/seq2) before the
//    barrier -> acc-init has no fresh LDS dependency after the barrier.
//  - epilogue per output: add(E+O) -> tanh -> cvt_pk -> b32 write.
__global__ __launch_bounds__(512, 2) void rnn_fused_kernel(
    const float* __restrict__ x,     // [B, 1024]
    const float* __restrict__ W1, const float* __restrict__ U1, const float* __restrict__ b1,
    const float* __restrict__ W2, const float* __restrict__ U2, const float* __restrict__ b2,
    float* __restrict__ h2out)       // [B, 256]
{
    const int tid  = threadIdx.x;
    const int w    = tid >> 6;
    const int lane = tid & 63;
    const int g    = lane >> 4;
    const int l16  = lane & 15;
    const int b0   = blockIdx.x << 4;

    __shared__ uint4 hbuf[2][512];       // 2 x 8KB, cell layout above
    __shared__ float xall[1024][16];     // 64KB: x staged [t][row]
    __shared__ float seq2[256][16];      // 16KB: layer-2 input [col][row]

    // ---- stage all of x (once) + zero h buffer 0 ----
    {
        const float4* x4 = (const float4*)x;
        #pragma unroll
        for (int i = 0; i < 8; ++i) {
            const int idx = tid + i * 512;
            const int row = idx >> 8, tq = idx & 255;
            const float4 v = x4[(b0 + row) * 256 + tq];
            xall[tq * 4 + 0][row] = v.x;
            xall[tq * 4 + 1][row] = v.y;
            xall[tq * 4 + 2][row] = v.z;
            xall[tq * 4 + 3][row] = v.w;
        }
        for (int idx = tid; idx < 2048; idx += 512)
            ((unsigned int*)hbuf[0])[idx] = 0u;
    }

    // ---- hoisted LDS byte offsets ----
    int rd_off[8];
    #pragma unroll
    for (int kk = 0; kk < 8; ++kk)
        rd_off[kk] = ((kk * 64 + g * 16) + (l16 ^ ((kk * 4 + g) & 15))) << 4;
    const int q = l16 >> 2, s4 = l16 & 3;
    int wr_off[4];
    #pragma unroll
    for (int r = 0; r < 4; ++r) {
        const int m = 4 * g + r;
        wr_off[r] = (((w * 64 + q * 16) + (m ^ ((4 * w + q) & 15))) << 4) + 4 * s4;
    }
    const int col0 = w * 32 + 2 * l16;
    char* const hbase = (char*)hbuf;

#pragma unroll 1
    for (int p = 0; p < 2; ++p) {
        const float* W    = p ? W2 : W1;
        const float* U    = p ? U2 : U1;
        const float* bias = p ? b2 : b1;
        const int    T    = p ? 256 : 1024;

        // ---- B-fragments (bf16, pinned registers); col = w*32 + 2c + t2 ----
        uint4 bfrag[2][8];
        #pragma unroll
        for (int t2 = 0; t2 < 2; ++t2) {
            #pragma unroll
            for (int kk = 0; kk < 8; ++kk) {
                unsigned int d[4];
                #pragma unroll
                for (int pr = 0; pr < 4; ++pr) {
                    const int k0 = kk * 32 + g * 8 + 2 * pr;
                    d[pr] = (unsigned)f2bf(U[k0 * 256 + col0 + t2])
                          | ((unsigned)f2bf(U[(k0 + 1) * 256 + col0 + t2]) << 16);
                }
                bfrag[t2][kk] = make_uint4(d[0], d[1], d[2], d[3]);
            }
        }
        #pragma unroll
        for (int t2 = 0; t2 < 2; ++t2)
            #pragma unroll
            for (int kk = 0; kk < 8; ++kk)
                asm volatile("" : "+v"(bfrag[t2][kk].x), "+v"(bfrag[t2][kk].y),
                                  "+v"(bfrag[t2][kk].z), "+v"(bfrag[t2][kk].w));

        const float2 wv2 = *(const float2*)&W[col0];
        const float2 bv2 = *(const float2*)&bias[col0];

        if (p == 1) {
            // re-zero h buffer 0 for layer 2
            for (int idx = tid; idx < 2048; idx += 512)
                ((unsigned int*)hbuf[0])[idx] = 0u;
        }
        __syncthreads();

        // prefetch sv for t=0 (xall/seq2 are static during the loop)
        float4 svc = p ? *(const float4*)&seq2[0][4 * g]
                       : *(const float4*)&xall[0][4 * g];

        for (int t = 0; t < T; ++t) {
            char* const hcur = hbase + ((t & 1) << 13);
            char* const hnxt = hbase + (((t & 1) ^ 1) << 13);

            // A-fragments: 8 x ds_read_b128, conflict-free
            uint4 a[8];
            #pragma unroll
            for (int kk = 0; kk < 8; ++kk)
                a[kk] = *(const uint4*)(hcur + rd_off[kk]);

            const float svr[4] = {svc.x, svc.y, svc.z, svc.w};

            // accE init = input projection + bias (overlaps ds_read latency);
            // accO starts at zero.
            f32x4 aA0, aA1;
            f32x4 aB0 = {0.f, 0.f, 0.f, 0.f}, aB1 = {0.f, 0.f, 0.f, 0.f};
            #pragma unroll
            for (int r = 0; r < 4; ++r) {
                aA0[r] = fmaf(svr[r], wv2.x, bv2.x);
                aA1[r] = fmaf(svr[r], wv2.y, bv2.y);
            }

            // 4 independent 4-deep MFMA chains (2 tiles x even/odd kk)
            #pragma unroll
            for (int kp = 0; kp < 4; ++kp) {
                aA0 = __builtin_amdgcn_mfma_f32_16x16x32_bf16(
                    as_s8(a[2 * kp]), as_s8(bfrag[0][2 * kp]), aA0, 0, 0, 0);
                aA1 = __builtin_amdgcn_mfma_f32_16x16x32_bf16(
                    as_s8(a[2 * kp]), as_s8(bfrag[1][2 * kp]), aA1, 0, 0, 0);
                aB0 = __builtin_amdgcn_mfma_f32_16x16x32_bf16(
                    as_s8(a[2 * kp + 1]), as_s8(bfrag[0][2 * kp + 1]), aB0, 0, 0, 0);
                aB1 = __builtin_amdgcn_mfma_f32_16x16x32_bf16(
                    as_s8(a[2 * kp + 1]), as_s8(bfrag[1][2 * kp + 1]), aB1, 0, 0, 0);
            }

            // prefetch sv for t+1 (static LDS, safe before the barrier)
            {
                const int tn = (t + 1 < T) ? t + 1 : t;
                svc = p ? *(const float4*)&seq2[tn][4 * g]
                        : *(const float4*)&xall[tn][4 * g];
            }

            #pragma unroll
            for (int r = 0; r < 4; ++r) {
                const float h0 = fast_tanh(aA0[r] + aB0[r]);
                const float h1 = fast_tanh(aA1[r] + aB1[r]);
                unsigned pk;
                asm("v_cvt_pk_bf16_f32 %0, %1, %2" : "=v"(pk) : "v"(h0), "v"(h1));
                *(unsigned int*)(hnxt + wr_off[r]) = pk;

                if (t == T - 1) {
                    const int m = 4 * g + r;
                    if (p == 0) {
                        seq2[col0][m]     = h0;
                        seq2[col0 + 1][m] = h1;
                    } else {
                        *(float2*)&h2out[(b0 + m) * 256 + col0] = make_float2(h0, h1);
                    }
                }
            }
            __syncthreads();
        }
    }
}

// Tiny MLP head: one block per batch row, 128 threads.
__global__ __launch_bounds__(128) void mlp_kernel(
    const float* __restrict__ h2,
    const float* __restrict__ Wd1, const float* __restrict__ bd1,
    const float* __restrict__ Wd2, const float* __restrict__ bd2,
    const float* __restrict__ Wd3, const float* __restrict__ bd3,
    const float* __restrict__ Wd4, const float* __restrict__ bd4,
    float* __restrict__ out)
{
    const int b   = blockIdx.x;
    const int tid = threadIdx.x;

    __shared__ float hin[256];
    __shared__ float z1[128];
    __shared__ float z2[64];
    __shared__ float z3[32];

    hin[tid]       = h2[b * 256 + tid];
    hin[tid + 128] = h2[b * 256 + tid + 128];
    __syncthreads();

    {
        float a = bd1[tid];
#pragma unroll 8
        for (int i = 0; i < 256; ++i) a += hin[i] * Wd1[i * 128 + tid];
        z1[tid] = fmaxf(a, 0.0f);
    }
    __syncthreads();
    if (tid < 64) {
        float a = bd2[tid];
#pragma unroll 8
        for (int i = 0; i < 128; ++i) a += z1[i] * Wd2[i * 64 + tid];
        z2[tid] = fmaxf(a, 0.0f);
    }
    __syncthreads();
    if (tid < 32) {
        float a = bd3[tid];
#pragma unroll 8
        for (int i = 0; i < 64; ++i) a += z2[i] * Wd3[i * 32 + tid];
        z3[tid] = fmaxf(a, 0.0f);
    }
    __syncthreads();
    if (tid < NCLS) {
        float a = bd4[tid];
#pragma unroll
        for (int i = 0; i < 32; ++i) a += z3[i] * Wd4[i * NCLS + tid];
        out[b * NCLS + tid] = a;
    }
}

extern "C" void kernel_launch(void* const* d_in, const int* in_sizes, int n_in,
                              void* d_out, int out_size, void* d_ws, size_t ws_size,
                              hipStream_t stream) {
    const float* x   = (const float*)d_in[0];
    const float* W1  = (const float*)d_in[1];
    const float* U1  = (const float*)d_in[2];
    const float* b1  = (const float*)d_in[3];
    const float* W2  = (const float*)d_in[4];
    const float* U2  = (const float*)d_in[5];
    const float* b2  = (const float*)d_in[6];
    const float* Wd1 = (const float*)d_in[7];
    const float* bd1 = (const float*)d_in[8];
    const float* Wd2 = (const float*)d_in[9];
    const float* bd2 = (const float*)d_in[10];
    const float* Wd3 = (const float*)d_in[11];
    const float* bd3 = (const float*)d_in[12];
    const float* Wd4 = (const float*)d_in[13];
    const float* bd4 = (const float*)d_in[14];

    float* out = (float*)d_out;
    float* h2  = (float*)d_ws;        // 512*256 fp32

    rnn_fused_kernel<<<32, 512, 0, stream>>>(x, W1, U1, b1, W2, U2, b2, h2);
    mlp_kernel<<<512, 128, 0, stream>>>(h2, Wd1, bd1, Wd2, bd2, Wd3, bd3, Wd4, bd4, out);
}